// Round 9
// baseline (257.992 us; speedup 1.0000x reference)
//
#include <hip/hip_runtime.h>

// irreps Linear: out[n, off_l + w*d + i] = 0.125 * sum_u x[n, off_l + u*d + i] * Wl[u][w]
// N=262144 rows of 576 = [64x(d=1) | 64x(d=3) | 64x(d=5)].
// History: R3 248 -> R8 238 us (scatter swizzle + full-line nt stores). 81% of
// copy ceiling. R9: wave-private epilogue. Each wave's output = a private
// 16-row x 144-float column strip; scatter goes to a per-wave LDS strip and
// copy-out is wave-private => the scatter/copy barriers (block-wide
// vmcnt(0)+lgkmcnt(0) drains) disappear. 4 barriers/tile -> 2.
// Strip runs are 64/192/320 B, 64B-aligned => full-line nt stores preserved.

typedef _Float16 half4  __attribute__((ext_vector_type(4)));
typedef float    f32x4  __attribute__((ext_vector_type(4)));

#define RPB      16                 // rows per block
#define NROWS    262144
#define ROWF     576                // floats per row
#define STRIP_B  9216               // per-wave out strip: 16 rows x 144 floats x 4 B
#define LDS_BYTES (4 * STRIP_B)     // 36864; stage region (18432) = strips 0-1, aliased

// ---- stage one l-segment of x into LDS as f16; LDS rows = (n_local*D + i), cols = u.
// XOR swizzle (row&7)<<4 breaks the 128B-stride same-bank pattern.
template<int D, int OFF, int SEGROW, int F4PR>   // F4PR = float4s per 576-f row in this seg
__device__ __forceinline__ void stage_seg(unsigned char* lds, const float* __restrict__ xrow0, int tid) {
#pragma unroll
  for (int it = 0; it < RPB * F4PR / 256; ++it) {  // 1 / 3 / 5 iters, no tail
    int t = tid + it * 256;
    int row = t / F4PR;                 // const divisor -> magic mul
    int f4  = t - row * F4PR;
    f32x4 v = *(const f32x4*)(xrow0 + (long long)row * ROWF + OFF + f4 * 4);
    int idx = f4 * 4;                   // element index within segment (= u*D + i)
    if (D == 1) {
      int lrow = SEGROW + row;
      int b = (lrow * 128 + idx * 2) ^ ((lrow & 7) << 4);
      half4 h = { (_Float16)v[0], (_Float16)v[1], (_Float16)v[2], (_Float16)v[3] };
      *(half4*)(lds + b) = h;           // 4 consecutive u: one 8B write
    } else {
#pragma unroll
      for (int j = 0; j < 4; ++j) {
        int u = (idx + j) / D;          // const divisor
        int i = (idx + j) - u * D;
        int lrow = SEGROW + row * D + i;
        int b = (lrow * 128 + u * 2) ^ ((lrow & 7) << 4);
        *(_Float16*)(lds + b) = (_Float16)v[j];
      }
    }
  }
}

// B-fragments for this wave's wt: bf[s][j] = W[u = s*16 + 4*laneq + j][w = wt*16 + lane15]
__device__ __forceinline__ void load_bfrag(const float* __restrict__ W, int wt,
                                           int lane15, int laneq, half4 bf[4]) {
  int w = wt * 16 + lane15;
#pragma unroll
  for (int s = 0; s < 4; ++s) {
    int u0 = s * 16 + laneq * 4;
#pragma unroll
    for (int j = 0; j < 4; ++j)
      bf[s][j] = (_Float16)W[(u0 + j) * 64 + w];   // 16-lane groups read 64B contig
  }
}

// MFMA all m-tiles of one l-segment for this wave's w-tile
template<int SEGROW, int MT>
__device__ __forceinline__ void compute_seg(const unsigned char* lds, int lane15, int laneq,
                                            const half4 bf[4], f32x4 acc[MT]) {
  const int coff = laneq * 8;           // k-chunk byte offset within a row
#pragma unroll
  for (int mt = 0; mt < MT; ++mt) {
    int arow  = SEGROW + mt * 16 + lane15;   // A: m = lane%16, k = s*16 + 4*laneq + j
    int abase = arow * 128;
    int aswz  = (arow & 7) << 4;
    acc[mt] = (f32x4){0.f, 0.f, 0.f, 0.f};
#pragma unroll
    for (int s = 0; s < 4; ++s) {
      half4 a = *(const half4*)(lds + abase + ((s * 32 + coff) ^ aswz));
      acc[mt] = __builtin_amdgcn_mfma_f32_16x16x16f16(a, bf[s], acc[mt], 0, 0, 0);
    }
  }
}

// scatter acc fragments into this wave's PRIVATE strip ([16 rows][144 floats],
// row stride 576 B). Strip cols: l0 -> 0..15, l1 -> 16..63, l2 -> 64..143.
// Byte addr XOR'd with (n&7)<<4 (involution, un-applied in copy-out).
template<int D, int SOFF, int MT>
__device__ __forceinline__ void scatter_strip(unsigned char* strip, int lane15, int laneq,
                                              const f32x4 acc[MT]) {
#pragma unroll
  for (int mt = 0; mt < MT; ++mt) {
#pragma unroll
    for (int j = 0; j < 4; ++j) {
      int r = mt * 16 + laneq * 4 + j;  // D-frag: col = lane&15 (w), row = 4*laneq + j
      int n = r / D;                    // const divisor
      int i = r - n * D;
      int col = SOFF + lane15 * D + i;  // local column within strip
      int b = (n * 576 + col * 4) ^ ((n & 7) << 4);
      *(float*)(strip + b) = 0.125f * acc[mt][j];
    }
  }
}

__global__ __launch_bounds__(256, 4) void linear_irreps(
    const float* __restrict__ x,
    const float* __restrict__ w0, const float* __restrict__ w1, const float* __restrict__ w2,
    float* __restrict__ out) {
  __shared__ __align__(16) unsigned char lds[LDS_BYTES];
  const int tid = threadIdx.x;
  const int lane = tid & 63, wave = tid >> 6;
  const int lane15 = lane & 15, laneq = lane >> 4;
  const int wt = wave;                  // 4 waves <-> 4 w-tiles (w = wt*16 .. +15)
  const long long base = (long long)blockIdx.x * (RPB * ROWF);

  // weights -> registers (L2-hot; latency overlaps x staging)
  half4 bf0[4], bf1[4], bf2[4];
  load_bfrag(w0, wt, lane15, laneq, bf0);
  load_bfrag(w1, wt, lane15, laneq, bf1);
  load_bfrag(w2, wt, lane15, laneq, bf2);

  // stage x tile (36 KB contiguous global span -> f16 LDS, [row(n,i)][u])
  stage_seg<1,   0,   0, 16>(lds, x + base, tid);
  stage_seg<3,  64,  16, 48>(lds, x + base, tid);
  stage_seg<5, 256,  64, 80>(lds, x + base, tid);
  __syncthreads();                      // staged data visible to all waves

  // MFMA into registers (36 f32 accs/thread)
  f32x4 acc1[1], acc3[3], acc5[5];
  compute_seg<  0, 1>(lds, lane15, laneq, bf0, acc1);
  compute_seg< 16, 3>(lds, lane15, laneq, bf1, acc3);
  compute_seg< 64, 5>(lds, lane15, laneq, bf2, acc5);
  __syncthreads();                      // all A-reads done; stage region dead

  // ---- wave-private epilogue: no more block barriers ----
  unsigned char* strip = lds + wt * STRIP_B;
  scatter_strip<1,   0, 1>(strip, lane15, laneq, acc1);
  scatter_strip<3,  16, 3>(strip, lane15, laneq, acc3);
  scatter_strip<5,  64, 5>(strip, lane15, laneq, acc5);
  // same-wave LDS RAW: compiler inserts wave-local lgkmcnt wait only

  // copy strip -> global: 9 x 16B chunks per lane; runs of 64/192/320 B per row,
  // all 64B-aligned => full-line nt stores.
#pragma unroll
  for (int k = 0; k < 9; ++k) {
    int t = lane + k * 64;              // 0..575
    int n = t / 36;                     // 36 chunks per row
    int q = t - n * 36;                 // 16B-chunk index within row
    int goff = (q < 4)  ? wt * 16 + q * 4
             : (q < 16) ? 64  + wt * 48 + (q - 4) * 4
                        : 256 + wt * 80 + (q - 16) * 4;
    f32x4 v = *(const f32x4*)(strip + ((n * 576 + q * 16) ^ ((n & 7) << 4)));
    __builtin_nontemporal_store(v, (f32x4*)(out + base + n * ROWF + goff));
  }
}

extern "C" void kernel_launch(void* const* d_in, const int* in_sizes, int n_in,
                              void* d_out, int out_size, void* d_ws, size_t ws_size,
                              hipStream_t stream) {
  const float* x  = (const float*)d_in[0];
  const float* w0 = (const float*)d_in[1];
  const float* w1 = (const float*)d_in[2];
  const float* w2 = (const float*)d_in[3];
  float* out = (float*)d_out;
  linear_irreps<<<NROWS / RPB, 256, 0, stream>>>(x, w0, w1, w2, out);
}

// Round 10
// 238.947 us; speedup vs baseline: 1.0797x; 1.0797x over previous
//
#include <hip/hip_runtime.h>

// irreps Linear: out[n, off_l + w*d + i] = 0.125 * sum_u x[n, off_l + u*d + i] * Wl[u][w]
// N=262144 rows of 576 = [64x(d=1) | 64x(d=3) | 64x(d=5)].
// R10 = restore R8 (238.4 us, best of 7 structural variants; R9's wave-private
// epilogue regressed to 258 because per-wave copy runs of 64/192/320 B broke
// full-line nt stores — block-contiguous 4KB-per-instruction copy wins).
// R8 = R3 base + (a) XOR involution (n&7)<<4 on out-tile LDS scatter addrs,
// (b) nontemporal FULL-LINE dwordx4 copy-out.
// 5.08 TB/s L2-side = 81% of m13 copy ceiling (6.29 TB/s).

typedef _Float16 half4  __attribute__((ext_vector_type(4)));
typedef float    f32x4  __attribute__((ext_vector_type(4)));

#define RPB      16                 // rows per block
#define NROWS    262144
#define ROWF     576                // floats per row
#define OUTBYTES (RPB * ROWF * 4)   // 36864 = out tile f32
#define LDS_BYTES OUTBYTES          // x-stage (18432 B) aliases the same buffer

// ---- stage one l-segment of x into LDS as f16; LDS rows = (n_local*D + i), cols = u.
// XOR swizzle (row&7)<<4 breaks the 128B-stride same-bank pattern.
template<int D, int OFF, int SEGROW, int F4PR>   // F4PR = float4s per 576-f row in this seg
__device__ __forceinline__ void stage_seg(unsigned char* lds, const float* __restrict__ xrow0, int tid) {
#pragma unroll
  for (int it = 0; it < RPB * F4PR / 256; ++it) {  // 1 / 3 / 5 iters, no tail
    int t = tid + it * 256;
    int row = t / F4PR;                 // const divisor -> magic mul
    int f4  = t - row * F4PR;
    f32x4 v = *(const f32x4*)(xrow0 + (long long)row * ROWF + OFF + f4 * 4);
    int idx = f4 * 4;                   // element index within segment (= u*D + i)
    if (D == 1) {
      int lrow = SEGROW + row;
      int b = (lrow * 128 + idx * 2) ^ ((lrow & 7) << 4);
      half4 h = { (_Float16)v[0], (_Float16)v[1], (_Float16)v[2], (_Float16)v[3] };
      *(half4*)(lds + b) = h;           // 4 consecutive u: one 8B write
    } else {
#pragma unroll
      for (int j = 0; j < 4; ++j) {
        int u = (idx + j) / D;          // const divisor
        int i = (idx + j) - u * D;
        int lrow = SEGROW + row * D + i;
        int b = (lrow * 128 + u * 2) ^ ((lrow & 7) << 4);
        *(_Float16*)(lds + b) = (_Float16)v[j];
      }
    }
  }
}

// B-fragments for this wave's wt: bf[s][j] = W[u = s*16 + 4*laneq + j][w = wt*16 + lane15]
__device__ __forceinline__ void load_bfrag(const float* __restrict__ W, int wt,
                                           int lane15, int laneq, half4 bf[4]) {
  int w = wt * 16 + lane15;
#pragma unroll
  for (int s = 0; s < 4; ++s) {
    int u0 = s * 16 + laneq * 4;
#pragma unroll
    for (int j = 0; j < 4; ++j)
      bf[s][j] = (_Float16)W[(u0 + j) * 64 + w];   // 16-lane groups read 64B contig
  }
}

// MFMA all m-tiles of one l-segment for this wave's w-tile
template<int SEGROW, int MT>
__device__ __forceinline__ void compute_seg(const unsigned char* lds, int lane15, int laneq,
                                            const half4 bf[4], f32x4 acc[MT]) {
  const int coff = laneq * 8;           // k-chunk byte offset within a row
#pragma unroll
  for (int mt = 0; mt < MT; ++mt) {
    int arow  = SEGROW + mt * 16 + lane15;   // A: m = lane%16, k = s*16 + 4*laneq + j
    int abase = arow * 128;
    int aswz  = (arow & 7) << 4;
    acc[mt] = (f32x4){0.f, 0.f, 0.f, 0.f};
#pragma unroll
    for (int s = 0; s < 4; ++s) {
      half4 a = *(const half4*)(lds + abase + ((s * 32 + coff) ^ aswz));
      acc[mt] = __builtin_amdgcn_mfma_f32_16x16x16f16(a, bf[s], acc[mt], 0, 0, 0);
    }
  }
}

// scatter acc fragments into the f32 out tile in LDS ([RPB][576] row-major),
// byte addr XOR'd with (n&7)<<4 (involution, un-applied in copy-out): spreads
// the 4 laneq-groups' bank sets apart within each ds_write.
template<int D, int OFF, int MT>
__device__ __forceinline__ void scatter_seg(unsigned char* lds, int wt, int lane15, int laneq,
                                            const f32x4 acc[MT]) {
  const int w = wt * 16 + lane15;
#pragma unroll
  for (int mt = 0; mt < MT; ++mt) {
#pragma unroll
    for (int j = 0; j < 4; ++j) {
      int r = mt * 16 + laneq * 4 + j;  // D-frag: col = lane&15, row = 4*laneq + j
      int n = r / D;                    // const divisor
      int i = r - n * D;
      int b = (n * (ROWF * 4) + (OFF + w * D + i) * 4) ^ ((n & 7) << 4);
      *(float*)(lds + b) = 0.125f * acc[mt][j];
    }
  }
}

__global__ __launch_bounds__(256, 4) void linear_irreps(
    const float* __restrict__ x,
    const float* __restrict__ w0, const float* __restrict__ w1, const float* __restrict__ w2,
    float* __restrict__ out) {
  __shared__ __align__(16) unsigned char lds[LDS_BYTES];
  const int tid = threadIdx.x;
  const int lane = tid & 63, wave = tid >> 6;
  const int lane15 = lane & 15, laneq = lane >> 4;
  const int wt = wave;                  // 4 waves <-> 4 w-tiles (w = wt*16 .. +15)
  const long long base = (long long)blockIdx.x * (RPB * ROWF);

  // weights -> registers (L2-hot; latency overlaps x staging)
  half4 bf0[4], bf1[4], bf2[4];
  load_bfrag(w0, wt, lane15, laneq, bf0);
  load_bfrag(w1, wt, lane15, laneq, bf1);
  load_bfrag(w2, wt, lane15, laneq, bf2);

  // stage x tile (36 KB contiguous global span -> f16 LDS, [row(n,i)][u])
  stage_seg<1,   0,   0, 16>(lds, x + base, tid);
  stage_seg<3,  64,  16, 48>(lds, x + base, tid);
  stage_seg<5, 256,  64, 80>(lds, x + base, tid);
  __syncthreads();

  // MFMA into registers (36 f32 accs/thread)
  f32x4 acc1[1], acc3[3], acc5[5];
  compute_seg<  0, 1>(lds, lane15, laneq, bf0, acc1);
  compute_seg< 16, 3>(lds, lane15, laneq, bf1, acc3);
  compute_seg< 64, 5>(lds, lane15, laneq, bf2, acc5);
  __syncthreads();                      // x-stage region dead before overwrite

  // scatter f32 results into LDS out tile (bank-spread XOR)
  scatter_seg<1,   0, 1>(lds, wt, lane15, laneq, acc1);
  scatter_seg<3,  64, 3>(lds, wt, lane15, laneq, acc3);
  scatter_seg<5, 256, 5>(lds, wt, lane15, laneq, acc5);
  __syncthreads();

  // fully-coalesced copy out: 9 x dwordx4 per thread, nontemporal (full lines;
  // keeps out from evicting x in L3). Un-apply the XOR spread.
#pragma unroll
  for (int k = 0; k < OUTBYTES / 4096; ++k) {      // 9
    int q = tid + k * 256;
    int n = q / 144;                    // 144 float4s per 576-f row
    f32x4 v = *(const f32x4*)(lds + ((q * 16) ^ ((n & 7) << 4)));
    __builtin_nontemporal_store(v, (f32x4*)(out + base + q * 4));
  }
}

extern "C" void kernel_launch(void* const* d_in, const int* in_sizes, int n_in,
                              void* d_out, int out_size, void* d_ws, size_t ws_size,
                              hipStream_t stream) {
  const float* x  = (const float*)d_in[0];
  const float* w0 = (const float*)d_in[1];
  const float* w1 = (const float*)d_in[2];
  const float* w2 = (const float*)d_in[3];
  float* out = (float*)d_out;
  linear_irreps<<<NROWS / RPB, 256, 0, stream>>>(x, w0, w1, w2, out);
}